// Round 21
// baseline (287.580 us; speedup 1.0000x reference)
//
#include <hip/hip_runtime.h>
#include <hip/hip_bf16.h>

typedef __attribute__((ext_vector_type(8))) short bf16x8_t;     // 8 bf16 (4 VGPRs)
typedef __attribute__((ext_vector_type(4))) float f32x4_t;
typedef __attribute__((ext_vector_type(16))) float f32x16_t;
typedef __attribute__((ext_vector_type(4))) unsigned short u16x4_t;
typedef __attribute__((ext_vector_type(2))) unsigned u32x2_t;

#define DEVINL __device__ __forceinline__

static constexpr int CN   = 256;    // channels
static constexpr int NSEQ = 1024;   // H*W
static constexpr int NH   = 8;      // heads
// 1/sqrt(32) * log2(e): folded into Q so attention uses native exp2
static constexpr float QSCALE = 0.17677669529663687f * 1.4426950408889634f;

DEVINL unsigned short f2bf(float f) {
    union { __hip_bfloat16 h; unsigned short u; } cv;
    cv.h = __float2bfloat16(f);
    return cv.u;
}

// single-instruction packed f32->bf16 pair (R5-verified: src0->lo, src1->hi)
DEVINL unsigned cvtpk_bf16(float lo, float hi) {
    unsigned r;
    asm("v_cvt_pk_bf16_f32 %0, %1, %2" : "=v"(r) : "v"(lo), "v"(hi));
    return r;
}

// partner-of-x across the lane^32 boundary (verified passing R5-R20).
// Semantics: swap(A,B) -> new_A={A.lo,B.lo}, new_B={A.hi,B.hi}
DEVINL float partner32_f(float x, int h2) {
    unsigned u = __builtin_bit_cast(unsigned, x);
    u32x2_t r = __builtin_amdgcn_permlane32_swap(u, u, false, false);
    return __builtin_bit_cast(float, h2 ? r.x : r.y);
}

// fast tanh for bf16 output: (t-1)/(t+1), t = 2^(2*log2e*x); |err| < 1e-6
DEVINL float fast_tanh(float x) {
    x = fminf(fmaxf(x, -20.f), 20.f);
    float t = __builtin_amdgcn_exp2f(2.8853900817779268f * x);
    return (t - 1.f) * __builtin_amdgcn_rcpf(t + 1.f);
}

// device-scope semaphore (d_ws counters, zeroed per launch by hipMemsetAsync).
// All 768 blocks are guaranteed co-resident (launch_bounds(256,3): 52KB LDS,
// VGPR cap ~170 >> used), so spin-wait cannot starve producers (G16-safe).
DEVINL void sem_signal(unsigned* c) {
    __syncthreads();                       // all block's work issued+drained
    if (threadIdx.x == 0) {
        __threadfence();                   // agent-scope visibility (cross-XCD)
        __hip_atomic_fetch_add(c, 1u, __ATOMIC_RELEASE, __HIP_MEMORY_SCOPE_AGENT);
    }
}
DEVINL void sem_wait(unsigned* c, unsigned target) {
    if (threadIdx.x == 0) {
        while (__hip_atomic_load(c, __ATOMIC_ACQUIRE, __HIP_MEMORY_SCOPE_AGENT) < target)
            __builtin_amdgcn_s_sleep(8);
        __threadfence();
    }
    __syncthreads();
}

// ---- ONE kernel, 3 phases. Bodies verbatim from the R20-best 3-kernel split;
// only the glue (grid-stride prep + semaphores) differs.
__global__ __launch_bounds__(256, 3) void fused_kernel(
        const float* __restrict__ seq,
        const float* __restrict__ Wq, const float* __restrict__ Wk, const float* __restrict__ Wv,
        const float* __restrict__ bq, const float* __restrict__ bk, const float* __restrict__ bv,
        unsigned short* __restrict__ Wbt, unsigned short* __restrict__ Sb,
        unsigned short* __restrict__ Qs, unsigned short* __restrict__ Kf,
        unsigned short* __restrict__ Vf, float* __restrict__ out,
        unsigned* __restrict__ sem) {
    __shared__ float comb[2][2][64][17];              // phase C only (17.4 KB)
    const int id  = blockIdx.x;                       // 768 blocks
    const int tid = threadIdx.x;

    // ================= phase A: prep (1792 units, grid-stride over 768 blocks)
    for (int v = id; v < 1792; v += 768) {
        if (v < 768) {
            int idx  = v * 256 + tid;                 // 768*256 elements
            int c    = idx & 255;
            int ncol = idx >> 8;
            int h = ncol / 96, r = ncol % 96;
            int t = r >> 5, d = r & 31;
            const float* W = (t == 0) ? Wq : (t == 1) ? Wk : Wv;
            Wbt[idx] = f2bf(W[((h << 8) + c) * 32 + d]);
        } else {
            int i = (v - 768) * 256 + tid;            // 262144 groups of 8
            const float4 x = ((const float4*)seq)[2 * i];
            const float4 y = ((const float4*)seq)[2 * i + 1];
            union { unsigned u[4]; bf16x8_t v8; } rv;
            rv.u[0] = cvtpk_bf16(x.x, x.y);
            rv.u[1] = cvtpk_bf16(x.z, x.w);
            rv.u[2] = cvtpk_bf16(y.x, y.y);
            rv.u[3] = cvtpk_bf16(y.z, y.w);
            *(bf16x8_t*)(Sb + (size_t)i * 8) = rv.v8;
        }
    }
    sem_signal(&sem[0]);
    sem_wait(&sem[0], 768);

    // ================= phase B: QKV projection GEMM (bx=id>>7, by=id&127)
    {
        const int bx = id >> 7, by = id & 127;
        const int w    = tid >> 6;
        const int lane = tid & 63;
        const int l15  = lane & 15, l4 = lane >> 4;
        const int mw = by * 64 + (w >> 1) * 32;       // wave: 32 rows x 64 cols
        const int nw = bx * 128 + (w & 1) * 64;

        f32x4_t acc[2][4];
        for (int mg = 0; mg < 2; ++mg)
            for (int g = 0; g < 4; ++g)
                acc[mg][g] = (f32x4_t){0.f, 0.f, 0.f, 0.f};

#pragma unroll
        for (int k0 = 0; k0 < CN; k0 += 32) {
            const int kk = k0 + l4 * 8;
            bf16x8_t a[2], b[4];
            for (int mg = 0; mg < 2; ++mg)
                a[mg] = *(const bf16x8_t*)(Sb + (size_t)(mw + mg * 16 + l15) * CN + kk);
            for (int g = 0; g < 4; ++g)
                b[g] = *(const bf16x8_t*)(Wbt + (size_t)(nw + g * 16 + l15) * CN + kk);
            for (int mg = 0; mg < 2; ++mg)
                for (int g = 0; g < 4; ++g)
                    acc[mg][g] = __builtin_amdgcn_mfma_f32_16x16x32_bf16(a[mg], b[g], acc[mg][g], 0, 0, 0);
        }

        for (int g = 0; g < 4; ++g) {
            const int ncol = nw + g * 16;             // 16-col group: uniform head/type
            const int h = ncol / 96, r = ncol % 96;
            const int t = r >> 5;
            const int d = (r & 31) + l15;
            for (int mg = 0; mg < 2; ++mg) {
                const int m0 = mw + mg * 16 + l4 * 4; // 4 consecutive global rows (same b)
                const int b_ = m0 >> 10;
                const int n0 = m0 & 1023;             // key index (multiple of 4)
                const int bh = b_ * NH + h;
                const int kt = n0 >> 5;
                if (t == 2) {                         // V: tanh, fragment-major 8B store
                    const float bias = bv[h * 32 + d];
                    u16x4_t vs;
                    for (int i = 0; i < 4; ++i)
                        vs[i] = f2bf(fast_tanh(acc[mg][g][i] + bias));
                    const size_t fidx = ((size_t)(bh * 32 + kt) * 2 + ((n0 >> 4) & 1)) * 64
                                        + d + 32 * ((n0 >> 3) & 1);
                    *(u16x4_t*)(Vf + fidx * 8 + (n0 & 7)) = vs;
                } else if (t == 0) {                  // Q: bias + scale(+log2e), row-major
                    const float bias = bq[h * 32 + d];
                    for (int i = 0; i < 4; ++i)
                        Qs[((size_t)bh * NSEQ + n0 + i) * 32 + d] = f2bf((acc[mg][g][i] + bias) * QSCALE);
                } else {                              // K: fragment-major scalar stores
                    const float bias = bk[h * 32 + d];
                    const size_t fbase = (((size_t)(bh * 32 + kt) * 2 + (d >> 4)) * 64
                                          + 32 * ((d >> 3) & 1)) * 8 + (d & 7);
                    for (int i = 0; i < 4; ++i)
                        Kf[fbase + (size_t)((n0 + i) & 31) * 8] = f2bf(acc[mg][g][i] + bias);
                }
            }
        }
    }
    sem_signal(&sem[1]);
    if (id >= 512) return;                            // blocks 512..767 done
    sem_wait(&sem[1], 768);

    // ================= phase C: flash attention (R17-best body, id<512)
    {
        const int lane = tid & 63;
        const int w    = tid >> 6;
        const int l31  = lane & 31;
        const int h2   = lane >> 5;
        const int qsel = w >> 1, ksel = w & 1;
        // XCD swizzle (bijective: 512 = 8 xcd x 8 bh_hi x 8 qt)
        const int bh = (id & 7) + 8 * ((id >> 3) & 7);
        const int qt = id >> 6;                       // 0..7
        const int b_ = bh >> 3, h = bh & 7;
        const int qbase = qt * 128 + qsel * 64;       // wave covers rows [qbase, qbase+64)

        // Q B-frags for both 32-row sub-tiles (col=q=lane&31, k=8*h2+j)
        const unsigned short* Qpa = Qs + ((size_t)bh * NSEQ + qbase + l31) * 32 + h2 * 8;
        const unsigned short* Qpb = Qpa + 32 * 32;    // +32 rows
        const bf16x8_t qf0a = *(const bf16x8_t*)(Qpa);
        const bf16x8_t qf1a = *(const bf16x8_t*)(Qpa + 16);
        const bf16x8_t qf0b = *(const bf16x8_t*)(Qpb);
        const bf16x8_t qf1b = *(const bf16x8_t*)(Qpb + 16);

        // own k-half: 16 tiles of 1024 fragment-major elements
        const unsigned short* Kp = Kf + (size_t)bh * 32768 + ksel * 16384 + lane * 8;
        const unsigned short* Vp = Vf + (size_t)bh * 32768 + ksel * 16384 + lane * 8;

        f32x16_t oa = {0.f,0.f,0.f,0.f,0.f,0.f,0.f,0.f,0.f,0.f,0.f,0.f,0.f,0.f,0.f,0.f};
        f32x16_t ob = {0.f,0.f,0.f,0.f,0.f,0.f,0.f,0.f,0.f,0.f,0.f,0.f,0.f,0.f,0.f,0.f};
        float la = 0.f, lb = 0.f;

        bf16x8_t kf0 = *(const bf16x8_t*)(Kp);
        bf16x8_t kf1 = *(const bf16x8_t*)(Kp + 512);
        bf16x8_t va0 = *(const bf16x8_t*)(Vp);
        bf16x8_t va1 = *(const bf16x8_t*)(Vp + 512);

#pragma unroll
        for (int kt = 0; kt < 16; ++kt) {             // 16 tiles per wave
            const int ktn = (kt + 1) & 15;            // wrap: no branch, no uninit
            bf16x8_t nk0 = *(const bf16x8_t*)(Kp + ktn * 1024);
            bf16x8_t nk1 = *(const bf16x8_t*)(Kp + ktn * 1024 + 512);
            bf16x8_t nv0 = *(const bf16x8_t*)(Vp + ktn * 1024);
            bf16x8_t nv1 = *(const bf16x8_t*)(Vp + ktn * 1024 + 512);

            // ---- sub-tile a ----
            {
                f32x16_t st = {0.f,0.f,0.f,0.f,0.f,0.f,0.f,0.f,0.f,0.f,0.f,0.f,0.f,0.f,0.f,0.f};
                __builtin_amdgcn_s_setprio(1);
                st = __builtin_amdgcn_mfma_f32_32x32x16_bf16(kf0, qf0a, st, 0, 0, 0);
                st = __builtin_amdgcn_mfma_f32_32x32x16_bf16(kf1, qf1a, st, 0, 0, 0);
                __builtin_amdgcn_s_setprio(0);
                float p[16];
#pragma unroll
                for (int r = 0; r < 16; ++r) p[r] = __builtin_amdgcn_exp2f(st[r]);
                float s8[8];
#pragma unroll
                for (int g = 0; g < 8; ++g) s8[g] = p[2 * g] + p[2 * g + 1];
                la += ((s8[0] + s8[1]) + (s8[2] + s8[3])) + ((s8[4] + s8[5]) + (s8[6] + s8[7]));
                unsigned pw[8];
#pragma unroll
                for (int g = 0; g < 8; ++g) pw[g] = cvtpk_bf16(p[2 * g], p[2 * g + 1]);
                u32x2_t s02 = __builtin_amdgcn_permlane32_swap(pw[0], pw[2], false, false);
                u32x2_t s13 = __builtin_amdgcn_permlane32_swap(pw[1], pw[3], false, false);
                u32x2_t s46 = __builtin_amdgcn_permlane32_swap(pw[4], pw[6], false, false);
                u32x2_t s57 = __builtin_amdgcn_permlane32_swap(pw[5], pw[7], false, false);
                union { unsigned u[4]; bf16x8_t v; } pb1, pb2;
                pb1.u[0] = s02.x; pb1.u[1] = s13.x; pb1.u[2] = s02.y; pb1.u[3] = s13.y;
                pb2.u[0] = s46.x; pb2.u[1] = s57.x; pb2.u[2] = s46.y; pb2.u[3] = s57.y;
                __builtin_amdgcn_s_setprio(1);
                oa = __builtin_amdgcn_mfma_f32_32x32x16_bf16(va0, pb1.v, oa, 0, 0, 0);
                oa = __builtin_amdgcn_mfma_f32_32x32x16_bf16(va1, pb2.v, oa, 0, 0, 0);
                __builtin_amdgcn_s_setprio(0);
            }
            // ---- sub-tile b ----
            {
                f32x16_t st = {0.f,0.f,0.f,0.f,0.f,0.f,0.f,0.f,0.f,0.f,0.f,0.f,0.f,0.f,0.f,0.f};
                __builtin_amdgcn_s_setprio(1);
                st = __builtin_amdgcn_mfma_f32_32x32x16_bf16(kf0, qf0b, st, 0, 0, 0);
                st = __builtin_amdgcn_mfma_f32_32x32x16_bf16(kf1, qf1b, st, 0, 0, 0);
                __builtin_amdgcn_s_setprio(0);
                float p[16];
#pragma unroll
                for (int r = 0; r < 16; ++r) p[r] = __builtin_amdgcn_exp2f(st[r]);
                float s8[8];
#pragma unroll
                for (int g = 0; g < 8; ++g) s8[g] = p[2 * g] + p[2 * g + 1];
                lb += ((s8[0] + s8[1]) + (s8[2] + s8[3])) + ((s8[4] + s8[5]) + (s8[6] + s8[7]));
                unsigned pw[8];
#pragma unroll
                for (int g = 0; g < 8; ++g) pw[g] = cvtpk_bf16(p[2 * g], p[2 * g + 1]);
                u32x2_t s02 = __builtin_amdgcn_permlane32_swap(pw[0], pw[2], false, false);
                u32x2_t s13 = __builtin_amdgcn_permlane32_swap(pw[1], pw[3], false, false);
                u32x2_t s46 = __builtin_amdgcn_permlane32_swap(pw[4], pw[6], false, false);
                u32x2_t s57 = __builtin_amdgcn_permlane32_swap(pw[5], pw[7], false, false);
                union { unsigned u[4]; bf16x8_t v; } pb1, pb2;
                pb1.u[0] = s02.x; pb1.u[1] = s13.x; pb1.u[2] = s02.y; pb1.u[3] = s13.y;
                pb2.u[0] = s46.x; pb2.u[1] = s57.x; pb2.u[2] = s46.y; pb2.u[3] = s57.y;
                __builtin_amdgcn_s_setprio(1);
                ob = __builtin_amdgcn_mfma_f32_32x32x16_bf16(va0, pb1.v, ob, 0, 0, 0);
                ob = __builtin_amdgcn_mfma_f32_32x32x16_bf16(va1, pb2.v, ob, 0, 0, 0);
                __builtin_amdgcn_s_setprio(0);
            }

            kf0 = nk0; kf1 = nk1; va0 = nv0; va1 = nv1;
        }

        const float lha = la + partner32_f(la, h2);
        const float lhb = lb + partner32_f(lb, h2);

        // cross-wave merge over ksel (exact: plain sums; no-max softmax)
        if (ksel) {
#pragma unroll
            for (int r = 0; r < 16; ++r) {
                comb[qsel][0][lane][r] = oa[r];
                comb[qsel][1][lane][r] = ob[r];
            }
            comb[qsel][0][lane][16] = lha;
            comb[qsel][1][lane][16] = lhb;
        }
        __syncthreads();
        if (!ksel) {
            {
                const float* c = comb[qsel][0][lane];
                const float inv = 1.0f / (lha + c[16]);
                float* op = out + ((size_t)(b_ * NSEQ + qbase + l31)) * 256 + h * 32 + h2 * 4;
#pragma unroll
                for (int g = 0; g < 4; ++g) {
                    float4 q4;
                    q4.x = (oa[4 * g + 0] + c[4 * g + 0]) * inv;
                    q4.y = (oa[4 * g + 1] + c[4 * g + 1]) * inv;
                    q4.z = (oa[4 * g + 2] + c[4 * g + 2]) * inv;
                    q4.w = (oa[4 * g + 3] + c[4 * g + 3]) * inv;
                    *(float4*)(op + 8 * g) = q4;
                }
            }
            {
                const float* c = comb[qsel][1][lane];
                const float inv = 1.0f / (lhb + c[16]);
                float* op = out + ((size_t)(b_ * NSEQ + qbase + 32 + l31)) * 256 + h * 32 + h2 * 4;
#pragma unroll
                for (int g = 0; g < 4; ++g) {
                    float4 q4;
                    q4.x = (ob[4 * g + 0] + c[4 * g + 0]) * inv;
                    q4.y = (ob[4 * g + 1] + c[4 * g + 1]) * inv;
                    q4.z = (ob[4 * g + 2] + c[4 * g + 2]) * inv;
                    q4.w = (ob[4 * g + 3] + c[4 * g + 3]) * inv;
                    *(float4*)(op + 8 * g) = q4;
                }
            }
        }
    }
}

extern "C" void kernel_launch(void* const* d_in, const int* in_sizes, int n_in,
                              void* d_out, int out_size, void* d_ws, size_t ws_size,
                              hipStream_t stream) {
    const float* seq = (const float*)d_in[0];
    // d_in[1] = ctx: unused by the reference computation
    const float* Wq = (const float*)d_in[2];
    const float* Wk = (const float*)d_in[3];
    const float* Wv = (const float*)d_in[4];
    const float* bq = (const float*)d_in[5];
    const float* bk = (const float*)d_in[6];
    const float* bv = (const float*)d_in[7];
    float* out = (float*)d_out;

    char* ws = (char*)d_ws;
    unsigned short* Wbt = (unsigned short*)ws;                          // 768*256*2   = 393216 B
    unsigned short* Qs  = (unsigned short*)(ws + 393216);               // 4 MiB
    unsigned short* Kf  = (unsigned short*)(ws + 393216 + 4194304);     // 4 MiB, fragment-major
    unsigned short* Vf  = (unsigned short*)(ws + 393216 + 2 * 4194304); // 4 MiB, fragment-major
    unsigned short* Sb  = (unsigned short*)(ws + 393216 + 3 * 4194304); // seq bf16 [8192][256]
    unsigned*       sem = (unsigned*)(ws + 393216 + 4 * 4194304);       // 2 counters

    hipMemsetAsync(sem, 0, 2 * sizeof(unsigned), stream);               // reset per call
    hipLaunchKernelGGL(fused_kernel, dim3(768), dim3(256), 0, stream,
                       seq, Wq, Wk, Wv, bq, bk, bv, Wbt, Sb, Qs, Kf, Vf, out, sem);
}

// Round 22
// 43.781 us; speedup vs baseline: 6.5686x; 6.5686x over previous
//
#include <hip/hip_runtime.h>
#include <hip/hip_bf16.h>

typedef __attribute__((ext_vector_type(8))) short bf16x8_t;     // 8 bf16 (4 VGPRs)
typedef __attribute__((ext_vector_type(4))) float f32x4_t;
typedef __attribute__((ext_vector_type(16))) float f32x16_t;
typedef __attribute__((ext_vector_type(4))) unsigned short u16x4_t;
typedef __attribute__((ext_vector_type(2))) unsigned u32x2_t;

#define DEVINL __device__ __forceinline__

static constexpr int CN   = 256;    // channels
static constexpr int NSEQ = 1024;   // H*W
static constexpr int NH   = 8;      // heads
// 1/sqrt(32) * log2(e): folded into Q so attention uses native exp2
static constexpr float QSCALE = 0.17677669529663687f * 1.4426950408889634f;

DEVINL unsigned short f2bf(float f) {
    union { __hip_bfloat16 h; unsigned short u; } cv;
    cv.h = __float2bfloat16(f);
    return cv.u;
}

// single-instruction packed f32->bf16 pair (R5-verified: src0->lo, src1->hi)
DEVINL unsigned cvtpk_bf16(float lo, float hi) {
    unsigned r;
    asm("v_cvt_pk_bf16_f32 %0, %1, %2" : "=v"(r) : "v"(lo), "v"(hi));
    return r;
}

// partner-of-x across the lane^32 boundary (verified passing R5-R21).
// Semantics: swap(A,B) -> new_A={A.lo,B.lo}, new_B={A.hi,B.hi}
DEVINL float partner32_f(float x, int h2) {
    unsigned u = __builtin_bit_cast(unsigned, x);
    u32x2_t r = __builtin_amdgcn_permlane32_swap(u, u, false, false);
    return __builtin_bit_cast(float, h2 ? r.x : r.y);
}

// fast tanh for bf16 output: (t-1)/(t+1), t = 2^(2*log2e*x); |err| < 1e-6
DEVINL float fast_tanh(float x) {
    x = fminf(fmaxf(x, -20.f), 20.f);
    float t = __builtin_amdgcn_exp2f(2.8853900817779268f * x);
    return (t - 1.f) * __builtin_amdgcn_rcpf(t + 1.f);
}

// ---- kernel 1 (prep DELETED): QKV projection GEMM  M=8192, K=256, N=768.
// Per-block W-pack into LDS with FULLY COALESCED loads: each bx covers exactly
// 4 complete 32-col t-slabs, each slab = contiguous W[h][0:256][d0:d0+32]
// (8192 floats, linear). A loaded fp32 + v_cvt_pk in-register (bit-identical
// to old prep). No inter-block dependency -> 3 kernels become 2.
__global__ __launch_bounds__(256) void proj_kernel(
        const float* __restrict__ seq,
        const float* __restrict__ Wq, const float* __restrict__ Wk, const float* __restrict__ Wv,
        const float* __restrict__ bq, const float* __restrict__ bk, const float* __restrict__ bv,
        unsigned short* __restrict__ Qs, unsigned short* __restrict__ Kf,
        unsigned short* __restrict__ Vf) {
    __shared__ __attribute__((aligned(16))) unsigned short Wl[128][280]; // 71.7KB; 560B rows: 16B-aligned, 2-way banks
    const int bx   = blockIdx.x;                      // 0..5
    const int by   = blockIdx.y;                      // 0..127
    const int tid  = threadIdx.x;
    const int w    = tid >> 6;
    const int lane = tid & 63;
    const int l15  = lane & 15, l4 = lane >> 4;
    const int mw = by * 64 + (w >> 1) * 32;           // wave: 32 rows x 64 cols
    const int nw = bx * 128 + (w & 1) * 64;

    // ---- coalesced W-pack: 4 slabs x 8192 contiguous floats -> Wl[col][k] ----
#pragma unroll
    for (int s = 0; s < 4; ++s) {
        const int ncol0 = bx * 128 + s * 32;          // multiple of 32 -> full slab
        const int h = ncol0 / 96, r = ncol0 % 96, t = r >> 5;
        const float* src = ((t == 0) ? Wq : (t == 1) ? Wk : Wv) + (size_t)h * 8192;
#pragma unroll
        for (int i = 0; i < 8; ++i) {
            const int idx4 = (i * 256 + tid) * 4;     // linear: coalesced float4
            const float4 v4 = *(const float4*)(src + idx4);
            const int c = idx4 >> 5;                  // k index
            const int d = idx4 & 31;                  // d, d+1, d+2, d+3 (d%4==0)
            Wl[s * 32 + d    ][c] = f2bf(v4.x);
            Wl[s * 32 + d + 1][c] = f2bf(v4.y);
            Wl[s * 32 + d + 2][c] = f2bf(v4.z);
            Wl[s * 32 + d + 3][c] = f2bf(v4.w);
        }
    }
    __syncthreads();

    f32x4_t acc[2][4];
    for (int mg = 0; mg < 2; ++mg)
        for (int g = 0; g < 4; ++g)
            acc[mg][g] = (f32x4_t){0.f, 0.f, 0.f, 0.f};

#pragma unroll
    for (int k0 = 0; k0 < CN; k0 += 32) {
        const int kk = k0 + l4 * 8;
        bf16x8_t a[2], b[4];
        for (int mg = 0; mg < 2; ++mg) {              // A: fp32 -> bf16 in-register
            const float* p = seq + (size_t)(mw + mg * 16 + l15) * CN + kk;
            const float4 x = *(const float4*)p;
            const float4 y = *(const float4*)(p + 4);
            union { unsigned u[4]; bf16x8_t v; } av;
            av.u[0] = cvtpk_bf16(x.x, x.y);
            av.u[1] = cvtpk_bf16(x.z, x.w);
            av.u[2] = cvtpk_bf16(y.x, y.y);
            av.u[3] = cvtpk_bf16(y.z, y.w);
            a[mg] = av.v;
        }
        for (int g = 0; g < 4; ++g)
            b[g] = *(const bf16x8_t*)(&Wl[(w & 1) * 64 + g * 16 + l15][kk]);
        for (int mg = 0; mg < 2; ++mg)
            for (int g = 0; g < 4; ++g)
                acc[mg][g] = __builtin_amdgcn_mfma_f32_16x16x32_bf16(a[mg], b[g], acc[mg][g], 0, 0, 0);
    }

    for (int g = 0; g < 4; ++g) {
        const int ncol = nw + g * 16;          // 16-col group: uniform head/type
        const int h = ncol / 96, r = ncol % 96;
        const int t = r >> 5;
        const int d = (r & 31) + l15;
        for (int mg = 0; mg < 2; ++mg) {
            const int m0 = mw + mg * 16 + l4 * 4;   // 4 consecutive global rows (same b)
            const int b_ = m0 >> 10;
            const int n0 = m0 & 1023;               // key index (multiple of 4)
            const int bh = b_ * NH + h;
            const int kt = n0 >> 5;
            if (t == 2) {                            // V: tanh, fragment-major 8B store
                const float bias = bv[h * 32 + d];
                u16x4_t vs;
                for (int i = 0; i < 4; ++i)
                    vs[i] = f2bf(fast_tanh(acc[mg][g][i] + bias));
                const size_t fidx = ((size_t)(bh * 32 + kt) * 2 + ((n0 >> 4) & 1)) * 64
                                    + d + 32 * ((n0 >> 3) & 1);
                *(u16x4_t*)(Vf + fidx * 8 + (n0 & 7)) = vs;
            } else if (t == 0) {                     // Q: bias + scale(+log2e), row-major
                const float bias = bq[h * 32 + d];
                for (int i = 0; i < 4; ++i)
                    Qs[((size_t)bh * NSEQ + n0 + i) * 32 + d] = f2bf((acc[mg][g][i] + bias) * QSCALE);
            } else {                                 // K: fragment-major scalar stores
                const float bias = bk[h * 32 + d];
                const size_t fbase = (((size_t)(bh * 32 + kt) * 2 + (d >> 4)) * 64
                                      + 32 * ((d >> 3) & 1)) * 8 + (d & 7);
                for (int i = 0; i < 4; ++i)
                    Kf[fbase + (size_t)((n0 + i) & 31) * 8] = f2bf(acc[mg][g][i] + bias);
            }
        }
    }
}

// ---- kernel 2: flash attention, 2-Q-TILE PER WAVE (R17/R20-best, verbatim).
__global__ __launch_bounds__(256, 2) void attn_kernel(
        const unsigned short* __restrict__ Qs, const unsigned short* __restrict__ Kf,
        const unsigned short* __restrict__ Vf, float* __restrict__ out) {
    __shared__ float comb[2][2][64][17];              // [qsel][ab][lane][o0..15 | l]
    const int lane = threadIdx.x & 63;
    const int w    = threadIdx.x >> 6;
    const int l31  = lane & 31;
    const int h2   = lane >> 5;
    const int qsel = w >> 1, ksel = w & 1;
    // XCD swizzle (bijective: 512 = 8 xcd x 8 bh_hi x 8 qt)
    const int id = blockIdx.x;
    const int bh = (id & 7) + 8 * ((id >> 3) & 7);
    const int qt = id >> 6;                           // 0..7
    const int b_ = bh >> 3, h = bh & 7;
    const int qbase = qt * 128 + qsel * 64;           // wave covers rows [qbase, qbase+64)

    // Q B-frags for both 32-row sub-tiles (col=q=lane&31, k=8*h2+j)
    const unsigned short* Qpa = Qs + ((size_t)bh * NSEQ + qbase + l31) * 32 + h2 * 8;
    const unsigned short* Qpb = Qpa + 32 * 32;        // +32 rows
    const bf16x8_t qf0a = *(const bf16x8_t*)(Qpa);
    const bf16x8_t qf1a = *(const bf16x8_t*)(Qpa + 16);
    const bf16x8_t qf0b = *(const bf16x8_t*)(Qpb);
    const bf16x8_t qf1b = *(const bf16x8_t*)(Qpb + 16);

    // own k-half: 16 tiles of 1024 fragment-major elements
    const unsigned short* Kp = Kf + (size_t)bh * 32768 + ksel * 16384 + lane * 8;
    const unsigned short* Vp = Vf + (size_t)bh * 32768 + ksel * 16384 + lane * 8;

    f32x16_t oa = {0.f,0.f,0.f,0.f,0.f,0.f,0.f,0.f,0.f,0.f,0.f,0.f,0.f,0.f,0.f,0.f};
    f32x16_t ob = {0.f,0.f,0.f,0.f,0.f,0.f,0.f,0.f,0.f,0.f,0.f,0.f,0.f,0.f,0.f,0.f};
    float la = 0.f, lb = 0.f;

    bf16x8_t kf0 = *(const bf16x8_t*)(Kp);
    bf16x8_t kf1 = *(const bf16x8_t*)(Kp + 512);
    bf16x8_t va0 = *(const bf16x8_t*)(Vp);
    bf16x8_t va1 = *(const bf16x8_t*)(Vp + 512);

#pragma unroll
    for (int kt = 0; kt < 16; ++kt) {                 // 16 tiles per wave
        const int ktn = (kt + 1) & 15;                // wrap: no branch, no uninit
        bf16x8_t nk0 = *(const bf16x8_t*)(Kp + ktn * 1024);
        bf16x8_t nk1 = *(const bf16x8_t*)(Kp + ktn * 1024 + 512);
        bf16x8_t nv0 = *(const bf16x8_t*)(Vp + ktn * 1024);
        bf16x8_t nv1 = *(const bf16x8_t*)(Vp + ktn * 1024 + 512);

        // ---- sub-tile a ----
        {
            f32x16_t st = {0.f,0.f,0.f,0.f,0.f,0.f,0.f,0.f,0.f,0.f,0.f,0.f,0.f,0.f,0.f,0.f};
            __builtin_amdgcn_s_setprio(1);
            st = __builtin_amdgcn_mfma_f32_32x32x16_bf16(kf0, qf0a, st, 0, 0, 0);
            st = __builtin_amdgcn_mfma_f32_32x32x16_bf16(kf1, qf1a, st, 0, 0, 0);
            __builtin_amdgcn_s_setprio(0);
            float p[16];
#pragma unroll
            for (int r = 0; r < 16; ++r) p[r] = __builtin_amdgcn_exp2f(st[r]);
            float s8[8];
#pragma unroll
            for (int g = 0; g < 8; ++g) s8[g] = p[2 * g] + p[2 * g + 1];
            la += ((s8[0] + s8[1]) + (s8[2] + s8[3])) + ((s8[4] + s8[5]) + (s8[6] + s8[7]));
            unsigned pw[8];
#pragma unroll
            for (int g = 0; g < 8; ++g) pw[g] = cvtpk_bf16(p[2 * g], p[2 * g + 1]);
            u32x2_t s02 = __builtin_amdgcn_permlane32_swap(pw[0], pw[2], false, false);
            u32x2_t s13 = __builtin_amdgcn_permlane32_swap(pw[1], pw[3], false, false);
            u32x2_t s46 = __builtin_amdgcn_permlane32_swap(pw[4], pw[6], false, false);
            u32x2_t s57 = __builtin_amdgcn_permlane32_swap(pw[5], pw[7], false, false);
            union { unsigned u[4]; bf16x8_t v; } pb1, pb2;
            pb1.u[0] = s02.x; pb1.u[1] = s13.x; pb1.u[2] = s02.y; pb1.u[3] = s13.y;
            pb2.u[0] = s46.x; pb2.u[1] = s57.x; pb2.u[2] = s46.y; pb2.u[3] = s57.y;
            __builtin_amdgcn_s_setprio(1);
            oa = __builtin_amdgcn_mfma_f32_32x32x16_bf16(va0, pb1.v, oa, 0, 0, 0);
            oa = __builtin_amdgcn_mfma_f32_32x32x16_bf16(va1, pb2.v, oa, 0, 0, 0);
            __builtin_amdgcn_s_setprio(0);
        }
        // ---- sub-tile b ----
        {
            f32x16_t st = {0.f,0.f,0.f,0.f,0.f,0.f,0.f,0.f,0.f,0.f,0.f,0.f,0.f,0.f,0.f,0.f};
            __builtin_amdgcn_s_setprio(1);
            st = __builtin_amdgcn_mfma_f32_32x32x16_bf16(kf0, qf0b, st, 0, 0, 0);
            st = __builtin_amdgcn_mfma_f32_32x32x16_bf16(kf1, qf1b, st, 0, 0, 0);
            __builtin_amdgcn_s_setprio(0);
            float p[16];
#pragma unroll
            for (int r = 0; r < 16; ++r) p[r] = __builtin_amdgcn_exp2f(st[r]);
            float s8[8];
#pragma unroll
            for (int g = 0; g < 8; ++g) s8[g] = p[2 * g] + p[2 * g + 1];
            lb += ((s8[0] + s8[1]) + (s8[2] + s8[3])) + ((s8[4] + s8[5]) + (s8[6] + s8[7]));
            unsigned pw[8];
#pragma unroll
            for (int g = 0; g < 8; ++g) pw[g] = cvtpk_bf16(p[2 * g], p[2 * g + 1]);
            u32x2_t s02 = __builtin_amdgcn_permlane32_swap(pw[0], pw[2], false, false);
            u32x2_t s13 = __builtin_amdgcn_permlane32_swap(pw[1], pw[3], false, false);
            u32x2_t s46 = __builtin_amdgcn_permlane32_swap(pw[4], pw[6], false, false);
            u32x2_t s57 = __builtin_amdgcn_permlane32_swap(pw[5], pw[7], false, false);
            union { unsigned u[4]; bf16x8_t v; } pb1, pb2;
            pb1.u[0] = s02.x; pb1.u[1] = s13.x; pb1.u[2] = s02.y; pb1.u[3] = s13.y;
            pb2.u[0] = s46.x; pb2.u[1] = s57.x; pb2.u[2] = s46.y; pb2.u[3] = s57.y;
            __builtin_amdgcn_s_setprio(1);
            ob = __builtin_amdgcn_mfma_f32_32x32x16_bf16(va0, pb1.v, ob, 0, 0, 0);
            ob = __builtin_amdgcn_mfma_f32_32x32x16_bf16(va1, pb2.v, ob, 0, 0, 0);
            __builtin_amdgcn_s_setprio(0);
        }

        kf0 = nk0; kf1 = nk1; va0 = nv0; va1 = nv1;
    }

    const float lha = la + partner32_f(la, h2);
    const float lhb = lb + partner32_f(lb, h2);

    // cross-wave merge over ksel (exact: plain sums; no-max softmax)
    if (ksel) {
#pragma unroll
        for (int r = 0; r < 16; ++r) {
            comb[qsel][0][lane][r] = oa[r];
            comb[qsel][1][lane][r] = ob[r];
        }
        comb[qsel][0][lane][16] = lha;
        comb[qsel][1][lane][16] = lhb;
    }
    __syncthreads();
    if (!ksel) {
        {
            const float* c = comb[qsel][0][lane];
            const float inv = 1.0f / (lha + c[16]);
            float* op = out + ((size_t)(b_ * NSEQ + qbase + l31)) * 256 + h * 32 + h2 * 4;
#pragma unroll
            for (int g = 0; g < 4; ++g) {
                float4 q4;
                q4.x = (oa[4 * g + 0] + c[4 * g + 0]) * inv;
                q4.y = (oa[4 * g + 1] + c[4 * g + 1]) * inv;
                q4.z = (oa[4 * g + 2] + c[4 * g + 2]) * inv;
                q4.w = (oa[4 * g + 3] + c[4 * g + 3]) * inv;
                *(float4*)(op + 8 * g) = q4;
            }
        }
        {
            const float* c = comb[qsel][1][lane];
            const float inv = 1.0f / (lhb + c[16]);
            float* op = out + ((size_t)(b_ * NSEQ + qbase + 32 + l31)) * 256 + h * 32 + h2 * 4;
#pragma unroll
            for (int g = 0; g < 4; ++g) {
                float4 q4;
                q4.x = (ob[4 * g + 0] + c[4 * g + 0]) * inv;
                q4.y = (ob[4 * g + 1] + c[4 * g + 1]) * inv;
                q4.z = (ob[4 * g + 2] + c[4 * g + 2]) * inv;
                q4.w = (ob[4 * g + 3] + c[4 * g + 3]) * inv;
                *(float4*)(op + 8 * g) = q4;
            }
        }
    }
}

extern "C" void kernel_launch(void* const* d_in, const int* in_sizes, int n_in,
                              void* d_out, int out_size, void* d_ws, size_t ws_size,
                              hipStream_t stream) {
    const float* seq = (const float*)d_in[0];
    // d_in[1] = ctx: unused by the reference computation
    const float* Wq = (const float*)d_in[2];
    const float* Wk = (const float*)d_in[3];
    const float* Wv = (const float*)d_in[4];
    const float* bq = (const float*)d_in[5];
    const float* bk = (const float*)d_in[6];
    const float* bv = (const float*)d_in[7];
    float* out = (float*)d_out;

    char* ws = (char*)d_ws;
    unsigned short* Qs = (unsigned short*)ws;                       // 4 MiB
    unsigned short* Kf = (unsigned short*)(ws + 4194304);           // 4 MiB, fragment-major
    unsigned short* Vf = (unsigned short*)(ws + 2 * 4194304);       // 4 MiB, fragment-major

    hipLaunchKernelGGL(proj_kernel, dim3(6, 128), dim3(256), 0, stream,
                       seq, Wq, Wk, Wv, bq, bk, bv, Qs, Kf, Vf);
    hipLaunchKernelGGL(attn_kernel, dim3(512), dim3(256), 0, stream, Qs, Kf, Vf, out);
}